// Round 7
// baseline (1937.204 us; speedup 1.0000x reference)
//
#include <hip/hip_runtime.h>
#include <hip/hip_bf16.h>
#include <stdint.h>
#include <math.h>

// ---------------------------------------------------------------------------
// PCN Exploration layer. B=4, S=1024, D=1024, NS=8, NT=10.
// hyp = a*(hidden + 0.1*expl) + (1-a)*cp + sum_j c_j*noise_j  (a=0.99^10)
// Round 7: wave-specialized producer/consumer k_fused. 512 thr (8 waves),
// waves 0-3 generate threefry hyp panels (double-buffered A0/A1 in LDS, bf16,
// + global hypPairs store); waves 4-7 run Y-GEMM/LN/relu/U-GEMM/energy on the
// previous panel. 4 matched barriers per half-panel; block = 64 rows = 4
// pipelined half-panels; grid 512; 1 block/CU (LDS 98.8KB). Producer VALU
// hides consumer MFMA/L2 latency on the same SIMD.
// ---------------------------------------------------------------------------

#define NS_ 8
#define B_ 4
#define S_ 1024
#define D_ 1024
#define NROWS (NS_*B_*S_)            // 32768
#define NELEM (1u<<25)
#define NH 4                          // half-panels (16 rows) per block

typedef __attribute__((ext_vector_type(8))) short short8;
typedef __attribute__((ext_vector_type(4))) float f32x4;

struct RngParams {
  uint32_t k0[10], k1[10];
  float coef[10];
  float aH, aCP;
};

// ----------------------------- threefry -----------------------------------
__host__ __device__ __forceinline__ uint32_t rotl32_(uint32_t x, int r) {
  return (x << r) | (x >> (32 - r));
}

__host__ __device__ __forceinline__ void tf2x32(uint32_t k0, uint32_t k1,
                                                uint32_t x0, uint32_t x1,
                                                uint32_t &o0, uint32_t &o1) {
  uint32_t k2 = k0 ^ k1 ^ 0x1BD11BDAu;
  x0 += k0; x1 += k1;
  x0 += x1; x1 = rotl32_(x1, 13); x1 ^= x0;
  x0 += x1; x1 = rotl32_(x1, 15); x1 ^= x0;
  x0 += x1; x1 = rotl32_(x1, 26); x1 ^= x0;
  x0 += x1; x1 = rotl32_(x1, 6);  x1 ^= x0;
  x0 += k1; x1 += k2 + 1u;
  x0 += x1; x1 = rotl32_(x1, 17); x1 ^= x0;
  x0 += x1; x1 = rotl32_(x1, 29); x1 ^= x0;
  x0 += x1; x1 = rotl32_(x1, 16); x1 ^= x0;
  x0 += x1; x1 = rotl32_(x1, 24); x1 ^= x0;
  x0 += k2; x1 += k0 + 2u;
  x0 += x1; x1 = rotl32_(x1, 13); x1 ^= x0;
  x0 += x1; x1 = rotl32_(x1, 15); x1 ^= x0;
  x0 += x1; x1 = rotl32_(x1, 26); x1 ^= x0;
  x0 += x1; x1 = rotl32_(x1, 6);  x1 ^= x0;
  x0 += k0; x1 += k1 + 3u;
  x0 += x1; x1 = rotl32_(x1, 17); x1 ^= x0;
  x0 += x1; x1 = rotl32_(x1, 29); x1 ^= x0;
  x0 += x1; x1 = rotl32_(x1, 16); x1 ^= x0;
  x0 += x1; x1 = rotl32_(x1, 24); x1 ^= x0;
  x0 += k1; x1 += k2 + 4u;
  x0 += x1; x1 = rotl32_(x1, 13); x1 ^= x0;
  x0 += x1; x1 = rotl32_(x1, 15); x1 ^= x0;
  x0 += x1; x1 = rotl32_(x1, 26); x1 ^= x0;
  x0 += x1; x1 = rotl32_(x1, 6);  x1 ^= x0;
  x0 += k2; x1 += k0 + 5u;
  o0 = x0; o1 = x1;
}

// bits -> N(0,1): XLA ErfInv32 poly; fast -log(1-x^2) via (1-x)(1+x)
__device__ __forceinline__ float bits_to_normal(uint32_t bits) {
  const float lo = -0.99999994f;
  float f = __uint_as_float((bits >> 9) | 0x3f800000u) - 1.0f;
  float x = fmaxf(lo, f * 2.0f + lo);
  float t = (1.0f - x) * (1.0f + x);
  float w = -__logf(t);
  float p;
  if (w < 5.0f) {
    w = w - 2.5f;
    p = 2.81022636e-08f;
    p = fmaf(p, w, 3.43273939e-07f);
    p = fmaf(p, w, -3.5233877e-06f);
    p = fmaf(p, w, -4.39150654e-06f);
    p = fmaf(p, w, 0.00021858087f);
    p = fmaf(p, w, -0.00125372503f);
    p = fmaf(p, w, -0.00417768164f);
    p = fmaf(p, w, 0.246640727f);
    p = fmaf(p, w, 1.50140941f);
  } else {
    w = sqrtf(w) - 3.0f;
    p = -0.000200214257f;
    p = fmaf(p, w, 0.000100950558f);
    p = fmaf(p, w, 0.00134934322f);
    p = fmaf(p, w, -0.00367342844f);
    p = fmaf(p, w, 0.00573950773f);
    p = fmaf(p, w, -0.0076224613f);
    p = fmaf(p, w, 0.00943887047f);
    p = fmaf(p, w, 1.00167406f);
    p = fmaf(p, w, 2.83297682f);
  }
  return 1.41421356f * (p * x);
}

__device__ __forceinline__ float noise10(const RngParams& P, uint32_t i) {
  float acc = 0.f;
  #pragma unroll
  for (int j = 0; j < 10; ++j) {
    uint32_t w0, w1;
    tf2x32(P.k0[j], P.k1[j], 0u, i, w0, w1);
    acc = fmaf(P.coef[j], bits_to_normal(w0 ^ w1), acc);
  }
  return acc;
}

__device__ __forceinline__ uint16_t bf16u(float x) {
  __hip_bfloat16 h = __float2bfloat16(x);
  return *(uint16_t*)&h;
}
__device__ __forceinline__ float bf2f(uint32_t u) {
  return __uint_as_float(u << 16);
}

// ----------------------------- small kernels -------------------------------
__global__ void k_ctxA(const float* __restrict__ hidden, float* __restrict__ part) {
  int b = blockIdx.x >> 6, ch = blockIdx.x & 63;
  const float* p = hidden + (size_t)b * (S_ * D_) + (size_t)ch * 16 * 1024;
  int tid = threadIdx.x;
  #pragma unroll
  for (int k = 0; k < 4; ++k) {
    int d = tid + k * 256;
    float s = 0.f;
    #pragma unroll
    for (int t = 0; t < 16; ++t) s += p[t * 1024 + d];
    part[(size_t)blockIdx.x * 1024 + d] = s;
  }
}
__global__ void k_ctxB(const float* __restrict__ part, float* __restrict__ ctx) {
  int idx = blockIdx.x * 256 + threadIdx.x;
  int b = idx >> 10, d = idx & 1023;
  float s = 0.f;
  #pragma unroll 8
  for (int c = 0; c < 64; ++c) s += part[((size_t)(b * 64 + c)) * 1024 + d];
  ctx[idx] = s * (1.0f / 1024.0f);
}

__global__ void k_fc1(const float* __restrict__ ctx, const float* __restrict__ W1,
                      const float* __restrict__ b1, float* __restrict__ t1) {
  __shared__ float red[4][64];
  int b = blockIdx.x >> 5;
  int j0 = (blockIdx.x & 31) * 64;
  int l = threadIdx.x & 63, w = threadIdx.x >> 6;
  int j = j0 + l;
  const float* c = ctx + b * 1024 + w * 256;
  const float* wp = W1 + (size_t)(w * 256) * 2048 + j;
  float s = 0.f;
  #pragma unroll 8
  for (int k = 0; k < 256; ++k) s += c[k] * wp[(size_t)k * 2048];
  red[w][l] = s; __syncthreads();
  if (w == 0)
    t1[b * 2048 + j] = red[0][l] + red[1][l] + red[2][l] + red[3][l] + b1[j];
}

__global__ void k_ln_relu(float* __restrict__ t1, const float* __restrict__ g,
                          const float* __restrict__ bb) {
  __shared__ float red[256];
  int row = blockIdx.x, tid = threadIdx.x;
  float* x = t1 + row * 2048;
  float v[8];
  #pragma unroll
  for (int q = 0; q < 8; ++q) v[q] = x[tid + q * 256];
  float s = 0.f;
  #pragma unroll
  for (int q = 0; q < 8; ++q) s += v[q];
  red[tid] = s; __syncthreads();
  for (int off = 128; off > 0; off >>= 1) { if (tid < off) red[tid] += red[tid + off]; __syncthreads(); }
  float m = red[0] * (1.0f / 2048.0f);
  __syncthreads();
  float s2 = 0.f;
  #pragma unroll
  for (int q = 0; q < 8; ++q) { float d = v[q] - m; s2 += d * d; }
  red[tid] = s2; __syncthreads();
  for (int off = 128; off > 0; off >>= 1) { if (tid < off) red[tid] += red[tid + off]; __syncthreads(); }
  float var = red[0] * (1.0f / 2048.0f);
  float rs = 1.0f / sqrtf(var + 1e-5f);
  #pragma unroll
  for (int q = 0; q < 8; ++q) {
    int j = tid + q * 256;
    float z = (v[q] - m) * rs * g[j] + bb[j];
    x[j] = fmaxf(z, 0.0f);
  }
}

__global__ void k_fc2(const float* __restrict__ t1, const float* __restrict__ W2,
                      const float* __restrict__ b2, const float* __restrict__ ctx,
                      const float* __restrict__ Ew1c, const float* __restrict__ Eb1,
                      float* __restrict__ cp, float* __restrict__ ce) {
  __shared__ float red[4][64];
  int b = blockIdx.x >> 4;
  int j0 = (blockIdx.x & 15) * 64;
  int l = threadIdx.x & 63, w = threadIdx.x >> 6;
  int j = j0 + l;
  float s = 0.f;
  if (blockIdx.y == 0) {
    const float* a = t1 + b * 2048 + w * 512;
    const float* wp = W2 + (size_t)(w * 512) * 1024 + j;
    #pragma unroll 8
    for (int k = 0; k < 512; ++k) s += a[k] * wp[(size_t)k * 1024];
  } else {
    const float* a = ctx + b * 1024 + w * 256;
    const float* wp = Ew1c + (size_t)(w * 256) * 1024 + j;
    #pragma unroll 8
    for (int k = 0; k < 256; ++k) s += a[k] * wp[(size_t)k * 1024];
  }
  red[w][l] = s; __syncthreads();
  if (w == 0) {
    float r = red[0][l] + red[1][l] + red[2][l] + red[3][l];
    if (blockIdx.y == 0) cp[b * 1024 + j] = r + b2[j];
    else                 ce[b * 1024 + j] = r + Eb1[j];
  }
}

// --------------- weight transpose + f32->bf16:  dst[N][K] = src[K][N] ------
__global__ void k_wcvt(const float* __restrict__ src, uint16_t* __restrict__ dst,
                       int K, int N) {
  __shared__ float tile[64][65];
  int n0 = blockIdx.x * 64, k0 = blockIdx.y * 64;
  int tid = threadIdx.x;
  #pragma unroll
  for (int i = 0; i < 16; ++i) {
    int lin = tid + i * 256;
    int tr = lin >> 6, tc = lin & 63;
    tile[tr][tc] = src[(size_t)(k0 + tr) * N + n0 + tc];
  }
  __syncthreads();
  #pragma unroll
  for (int i = 0; i < 8; ++i) {
    int lin = tid + i * 256;
    int tr = lin >> 5, tc2 = (lin & 31) * 2;
    uint32_t pk = (uint32_t)bf16u(tile[tc2][tr]) | ((uint32_t)bf16u(tile[tc2 + 1][tr]) << 16);
    *(uint32_t*)(&dst[(size_t)(n0 + tr) * K + k0 + tc2]) = pk;
  }
}

// ----------------------------- fused energy (producer/consumer) ------------
// LDS layout (bytes): A0 @0 (32K) | A1 @32768 (32K) | ZP @65536 (32K) |
//                     rowm @98304 | rowr @98368 | red @98432 (256B)
#define A0_OF 0
#define A1_OF 32768
#define ZP_OF 65536
#define STM_OF 98304
#define STR_OF 98368
#define RED_OF 98432

__device__ __forceinline__ int pswz(int row, int byteInRow) {   // panel swizzle
  return (row * 2048 + byteInRow) ^ ((row & 7) << 4);
}

template<bool BIG>
__global__ __launch_bounds__(512, 2) void k_fused(
    const float* __restrict__ hidden, const float* __restrict__ cp,
    const float* __restrict__ ce, uint32_t* __restrict__ hypPairs,
    const uint16_t* __restrict__ WT1, const uint16_t* __restrict__ WT2,
    const float* __restrict__ Eln_g, const float* __restrict__ Eln_b,
    const float* __restrict__ Eb2, const float* __restrict__ Ew3,
    float* __restrict__ erows, RngParams P)
{
  __shared__ __align__(16) char smem[98688 + 128];
  const int tid = threadIdx.x;
  const int lane = tid & 63;
  const int rl = lane & 15;
  const int kg = lane >> 4;
  const int base_r0 = blockIdx.x * (NH * 16);
  const int bidx = (base_r0 >> 10) & 3;          // const: 64 rows within segment
  const bool producer = (tid < 256);
  const int ct = tid - 256;                      // consumer-local tid
  const int cw = ct >> 6;                        // consumer wave 0..3
  float* rowm = (float*)(smem + STM_OF);
  float* rowr = (float*)(smem + STR_OF);
  float* red  = (float*)(smem + RED_OF);

  // ---- head: gen A[0] with ALL 512 threads ----
  for (int q = 0; q < 16; ++q) {
    int p = tid + q * 512;
    int row = p >> 9, c0 = (p & 511) * 2;
    uint32_t i0 = (uint32_t)(base_r0 + row) * 1024u + (uint32_t)c0;
    float nz0 = noise10(P, i0);
    float nz1 = noise10(P, i0 + 1u);
    float2 hv = *(const float2*)(hidden + (i0 & 0x3FFFFFu));
    float2 cv = *(const float2*)(cp + (bidx << 10) + c0);
    uint32_t pk = (uint32_t)bf16u(fmaf(P.aH, hv.x, fmaf(P.aCP, cv.x, nz0))) |
                  ((uint32_t)bf16u(fmaf(P.aH, hv.y, fmaf(P.aCP, cv.y, nz1))) << 16);
    *(uint32_t*)(smem + A0_OF + pswz(row, c0 * 2)) = pk;
    if (BIG) hypPairs[i0 >> 1] = pk;
  }
  __syncthreads();

  // producer gen chunk s (8 of 32 iters) into buffer An for row-base nr0
#define GENCHUNK(s)                                                          \
  do {                                                                       \
    for (int q = (s) * 8; q < (s) * 8 + 8; ++q) {                            \
      int p = tid + q * 256;                                                 \
      int row = p >> 9, c0 = (p & 511) * 2;                                  \
      uint32_t i0 = (uint32_t)(nr0 + row) * 1024u + (uint32_t)c0;            \
      float nz0 = noise10(P, i0);                                            \
      float nz1 = noise10(P, i0 + 1u);                                       \
      float2 hv = *(const float2*)(hidden + (i0 & 0x3FFFFFu));               \
      float2 cv = *(const float2*)(cp + (bidx << 10) + c0);                  \
      uint32_t pk = (uint32_t)bf16u(fmaf(P.aH, hv.x, fmaf(P.aCP, cv.x, nz0))) | \
                    ((uint32_t)bf16u(fmaf(P.aH, hv.y, fmaf(P.aCP, cv.y, nz1))) << 16); \
      *(uint32_t*)(An + pswz(row, c0 * 2)) = pk;                             \
      if (BIG) hypPairs[i0 >> 1] = pk;                                       \
    }                                                                        \
  } while (0)

  for (int h = 0; h < NH; ++h) {
    const int r0 = base_r0 + h * 16;
    char* Ac = smem + ((h & 1) ? A1_OF : A0_OF);
    char* An = smem + ((h & 1) ? A0_OF : A1_OF);
    const uint32_t nr0 = (uint32_t)(r0 + 16);
    const bool gen = (h + 1 < NH);

    // ---------------- s0: phase2 (Y = Ac@WT1 + ce -> ZP) ----------------
    if (producer) {
      if (gen) GENCHUNK(0);
    } else {
      if (h > 0 && ct < 16)       // deferred erows write for previous panel
        erows[r0 - 16 + ct] = red[ct] + red[16 + ct] + red[32 + ct] + red[48 + ct];
      for (int g = 0; g < 4; ++g) {
        f32x4 acc[4] = {};
        const uint16_t* b0 = WT1 + (size_t)(g * 256 + cw * 64 +  0 + rl) * 1024 + kg * 8;
        const uint16_t* b1p = WT1 + (size_t)(g * 256 + cw * 64 + 16 + rl) * 1024 + kg * 8;
        const uint16_t* b2p = WT1 + (size_t)(g * 256 + cw * 64 + 32 + rl) * 1024 + kg * 8;
        const uint16_t* b3p = WT1 + (size_t)(g * 256 + cw * 64 + 48 + rl) * 1024 + kg * 8;
        #pragma unroll 4
        for (int kt = 0; kt < 32; ++kt) {
          short8 af = *(const short8*)(Ac + pswz(rl, kt * 64 + kg * 16));
          short8 f0 = *(const short8*)(b0  + kt * 32);
          short8 f1 = *(const short8*)(b1p + kt * 32);
          short8 f2 = *(const short8*)(b2p + kt * 32);
          short8 f3 = *(const short8*)(b3p + kt * 32);
          acc[0] = __builtin_amdgcn_mfma_f32_16x16x32_bf16(af, f0, acc[0], 0, 0, 0);
          acc[1] = __builtin_amdgcn_mfma_f32_16x16x32_bf16(af, f1, acc[1], 0, 0, 0);
          acc[2] = __builtin_amdgcn_mfma_f32_16x16x32_bf16(af, f2, acc[2], 0, 0, 0);
          acc[3] = __builtin_amdgcn_mfma_f32_16x16x32_bf16(af, f3, acc[3], 0, 0, 0);
        }
        #pragma unroll
        for (int j = 0; j < 4; ++j) {
          int C = g * 256 + cw * 64 + j * 16 + rl;
          float cev = ce[(bidx << 10) + C];
          #pragma unroll
          for (int i = 0; i < 4; ++i) {
            int row = kg * 4 + i;
            *(uint16_t*)(smem + ZP_OF + pswz(row, C * 2)) = bf16u(acc[j][i] + cev);
          }
        }
      }
    }
    __syncthreads();

    // ---------------- s1: LN stats ----------------
    if (producer) {
      if (gen) GENCHUNK(1);
    } else if (ct < 128) {
      int row = ct >> 3, l8 = ct & 7;
      float s1 = 0.f, s2 = 0.f;
      for (int j = 0; j < 128; ++j) {
        int c = l8 + j * 8;
        float v = bf2f(*(const uint16_t*)(smem + ZP_OF + pswz(row, c * 2)));
        s1 += v; s2 = fmaf(v, v, s2);
      }
      #pragma unroll
      for (int o = 4; o > 0; o >>= 1) {
        s1 += __shfl_down(s1, o, 8);
        s2 += __shfl_down(s2, o, 8);
      }
      if (l8 == 0) {
        float m = s1 * (1.0f / 1024.0f);
        float var = fmaxf(s2 * (1.0f / 1024.0f) - m * m, 0.0f);
        rowm[row] = m;
        rowr[row] = 1.0f / sqrtf(var + 1e-5f);
      }
    }
    __syncthreads();

    // ---------------- s2: Z = relu(LN(Y)) in place ----------------
    if (producer) {
      if (gen) GENCHUNK(2);
    } else {
      for (int q = 0; q < 64; ++q) {
        int e = ct + q * 256;
        int row = e >> 10, col = e & 1023;
        uint16_t* zp = (uint16_t*)(smem + ZP_OF + pswz(row, col * 2));
        float v = bf2f(*zp);
        float z = (v - rowm[row]) * rowr[row] * Eln_g[col] + Eln_b[col];
        *zp = bf16u(fmaxf(z, 0.f));
      }
    }
    __syncthreads();

    // ---------------- s3: U = relu(Z@WT2+Eb2); ep = U.Ew3 -> red ----------
    if (producer) {
      if (gen) GENCHUNK(3);
    } else {
      float ep0 = 0.f, ep1 = 0.f, ep2 = 0.f, ep3 = 0.f;
      for (int g = 0; g < 2; ++g) {
        f32x4 acc[4] = {};
        const uint16_t* b0 = WT2 + (size_t)(g * 256 + cw * 64 +  0 + rl) * 1024 + kg * 8;
        const uint16_t* b1p = WT2 + (size_t)(g * 256 + cw * 64 + 16 + rl) * 1024 + kg * 8;
        const uint16_t* b2p = WT2 + (size_t)(g * 256 + cw * 64 + 32 + rl) * 1024 + kg * 8;
        const uint16_t* b3p = WT2 + (size_t)(g * 256 + cw * 64 + 48 + rl) * 1024 + kg * 8;
        #pragma unroll 4
        for (int kt = 0; kt < 32; ++kt) {
          short8 af = *(const short8*)(smem + ZP_OF + pswz(rl, kt * 64 + kg * 16));
          short8 f0 = *(const short8*)(b0  + kt * 32);
          short8 f1 = *(const short8*)(b1p + kt * 32);
          short8 f2 = *(const short8*)(b2p + kt * 32);
          short8 f3 = *(const short8*)(b3p + kt * 32);
          acc[0] = __builtin_amdgcn_mfma_f32_16x16x32_bf16(af, f0, acc[0], 0, 0, 0);
          acc[1] = __builtin_amdgcn_mfma_f32_16x16x32_bf16(af, f1, acc[1], 0, 0, 0);
          acc[2] = __builtin_amdgcn_mfma_f32_16x16x32_bf16(af, f2, acc[2], 0, 0, 0);
          acc[3] = __builtin_amdgcn_mfma_f32_16x16x32_bf16(af, f3, acc[3], 0, 0, 0);
        }
        #pragma unroll
        for (int j = 0; j < 4; ++j) {
          int C = g * 256 + cw * 64 + j * 16 + rl;
          float eb = Eb2[C], w3 = Ew3[C];
          ep0 = fmaf(fmaxf(acc[j][0] + eb, 0.f), w3, ep0);
          ep1 = fmaf(fmaxf(acc[j][1] + eb, 0.f), w3, ep1);
          ep2 = fmaf(fmaxf(acc[j][2] + eb, 0.f), w3, ep2);
          ep3 = fmaf(fmaxf(acc[j][3] + eb, 0.f), w3, ep3);
        }
      }
      #pragma unroll
      for (int m = 1; m < 16; m <<= 1) {
        ep0 += __shfl_xor(ep0, m);
        ep1 += __shfl_xor(ep1, m);
        ep2 += __shfl_xor(ep2, m);
        ep3 += __shfl_xor(ep3, m);
      }
      if (rl == 0) {
        red[cw * 16 + kg * 4 + 0] = ep0;
        red[cw * 16 + kg * 4 + 1] = ep1;
        red[cw * 16 + kg * 4 + 2] = ep2;
        red[cw * 16 + kg * 4 + 3] = ep3;
      }
    }
    __syncthreads();
  }
#undef GENCHUNK

  // drain: erows for the last half-panel
  if (!producer && ct < 16)
    erows[base_r0 + (NH - 1) * 16 + ct] =
        red[ct] + red[16 + ct] + red[32 + ct] + red[48 + ct];
}

// energies[nb] = mean_s erows + Eb3
__global__ void k_energy(const float* __restrict__ erows, const float* __restrict__ Eb3,
                         float* __restrict__ energ) {
  __shared__ float red[256];
  int nb = blockIdx.x, tid = threadIdx.x;
  const float* x = erows + nb * 1024;
  float s = x[tid] + x[tid + 256] + x[tid + 512] + x[tid + 768];
  red[tid] = s; __syncthreads();
  for (int off = 128; off > 0; off >>= 1) { if (tid < off) red[tid] += red[tid + off]; __syncthreads(); }
  if (tid == 0) energ[nb] = red[0] * (1.0f / 1024.0f) + Eb3[0];
}

// ----------------------------- select --------------------------------------
template<bool BIG>
__global__ __launch_bounds__(256) void k_select(
    const float* __restrict__ hidden, const float* __restrict__ cp,
    const float* __restrict__ energ, const uint32_t* __restrict__ hypPairs,
    float* __restrict__ out, RngParams P)
{
  uint32_t pe = blockIdx.x * 256u + threadIdx.x;   // pair in [0, 2^21)
  uint32_t i0 = pe * 2u;
  uint32_t b = (i0 >> 20) & 3u;
  float e[8];
  #pragma unroll
  for (int n = 0; n < 8; ++n) e[n] = -energ[n * 4 + b];
  float mx = e[0];
  #pragma unroll
  for (int n = 1; n < 8; ++n) mx = fmaxf(mx, e[n]);
  float p[8]; float s = 0.f;
  #pragma unroll
  for (int n = 0; n < 8; ++n) { p[n] = expf(e[n] - mx); s += p[n]; }
  float inv = 1.0f / s;
  float a0 = 0.f, a1 = 0.f;
  if (BIG) {
    #pragma unroll
    for (int n = 0; n < 8; ++n) {
      uint32_t pk = hypPairs[pe + ((uint32_t)n << 21)];
      a0 = fmaf(p[n], __uint_as_float(pk << 16), a0);           // low bf16
      a1 = fmaf(p[n], __uint_as_float(pk & 0xffff0000u), a1);   // high bf16
    }
    *(float2*)(out + i0) = make_float2(a0 * inv, a1 * inv);
  } else {
    float2 hv = *(const float2*)(hidden + i0);
    float2 cv = *(const float2*)(cp + ((b << 10) | (i0 & 1023u)));
    #pragma unroll
    for (int n = 0; n < 8; ++n) {
      a0 = fmaf(p[n], noise10(P, i0 + ((uint32_t)n << 22)), a0);
      a1 = fmaf(p[n], noise10(P, i0 + 1u + ((uint32_t)n << 22)), a1);
    }
    float o0 = fmaf(P.aH, hv.x, P.aCP * cv.x) + a0 * inv;
    float o1 = fmaf(P.aH, hv.y, P.aCP * cv.y) + a1 * inv;
    *(float2*)(out + i0) = make_float2(o0, o1);
  }
}

// ---------------------------------------------------------------------------
extern "C" void kernel_launch(void* const* d_in, const int* in_sizes, int n_in,
                              void* d_out, int out_size, void* d_ws, size_t ws_size,
                              hipStream_t stream) {
  const float* hidden = (const float*)d_in[0];
  const float* W1    = (const float*)d_in[1];
  const float* b1    = (const float*)d_in[2];
  const float* ln1_g = (const float*)d_in[3];
  const float* ln1_b = (const float*)d_in[4];
  const float* W2    = (const float*)d_in[5];
  const float* b2    = (const float*)d_in[6];
  const float* Ew1   = (const float*)d_in[7];
  const float* Eb1   = (const float*)d_in[8];
  const float* Eln_g = (const float*)d_in[9];
  const float* Eln_b = (const float*)d_in[10];
  const float* Ew2   = (const float*)d_in[11];
  const float* Eb2   = (const float*)d_in[12];
  const float* Ew3   = (const float*)d_in[13];
  const float* Eb3   = (const float*)d_in[14];
  float* out = (float*)d_out;

  // ws carve: hyp-bf16 64 MiB + WT1 2 MiB + WT2 1 MiB + part 1 MiB + smalls
  const size_t HYP_B  = (size_t)NELEM * 2;           // 64 MiB (bf16 pairs)
  const size_t WT1_B  = 1024ull * 1024 * 2;          // 2 MiB
  const size_t WT2_B  = 512ull * 1024 * 2;           // 1 MiB
  const size_t PART_B = 256ull * 1024 * 4;           // 1 MiB
  const size_t SMALL_B = (4096 + 8192 + 4096 + 4096 + 32768 + 32) * 4;
  bool big = ws_size >= HYP_B + WT1_B + WT2_B + PART_B + SMALL_B + 1024;

  char* ws = (char*)d_ws;
  uint32_t* hypPairs = nullptr;
  size_t off = 0;
  if (big) { hypPairs = (uint32_t*)ws; off += HYP_B; }
  uint16_t* WT1 = (uint16_t*)(ws + off); off += WT1_B;
  uint16_t* WT2 = (uint16_t*)(ws + off); off += WT2_B;
  float* part  = (float*)(ws + off);     off += PART_B;
  float* ctx   = (float*)(ws + off);
  float* t1    = ctx + 4096;
  float* cp    = t1 + 8192;
  float* ce    = cp + 4096;
  float* erows = ce + 4096;
  float* energ = erows + 32768;

  // host-side RNG params
  RngParams P;
  for (uint32_t t = 0; t < 10; ++t) {
    uint32_t o0, o1;
    tf2x32(0u, 42u, 0u, t, o0, o1);
    P.k0[t] = o0; P.k1[t] = o1;
  }
  double a = pow(0.99, 10);
  P.coef[0] = (float)(0.1 * a);
  for (int j = 1; j <= 9; ++j) P.coef[j] = (float)(0.01 * pow(0.99, 10 - j));
  P.aH = (float)a;
  P.aCP = (float)(1.0 - a);

  k_wcvt<<<dim3(16, 16), 256, 0, stream>>>(Ew1, WT1, 1024, 1024);  // Ew1_h^T bf16
  k_wcvt<<<dim3(8, 16), 256, 0, stream>>>(Ew2, WT2, 1024, 512);    // Ew2^T bf16
  k_ctxA<<<256, 256, 0, stream>>>(hidden, part);
  k_ctxB<<<16, 256, 0, stream>>>(part, ctx);
  k_fc1<<<128, 256, 0, stream>>>(ctx, W1, b1, t1);
  k_ln_relu<<<4, 256, 0, stream>>>(t1, ln1_g, ln1_b);
  k_fc2<<<dim3(64, 2), 256, 0, stream>>>(t1, W2, b2, ctx, Ew1 + (size_t)1024 * 1024, Eb1, cp, ce);
  if (big)
    k_fused<true><<<NROWS / (NH * 16), 512, 0, stream>>>(hidden, cp, ce, hypPairs, WT1, WT2,
                                                         Eln_g, Eln_b, Eb2, Ew3, erows, P);
  else
    k_fused<false><<<NROWS / (NH * 16), 512, 0, stream>>>(hidden, cp, ce, nullptr, WT1, WT2,
                                                          Eln_g, Eln_b, Eb2, Ew3, erows, P);
  k_energy<<<32, 256, 0, stream>>>(erows, Eb3, energ);
  if (big)
    k_select<true><<<8192, 256, 0, stream>>>(hidden, cp, energ, hypPairs, out, P);
  else
    k_select<false><<<8192, 256, 0, stream>>>(hidden, cp, energ, nullptr, out, P);
}

// Round 8
// 1096.674 us; speedup vs baseline: 1.7664x; 1.7664x over previous
//
#include <hip/hip_runtime.h>
#include <hip/hip_bf16.h>
#include <stdint.h>
#include <math.h>

// ---------------------------------------------------------------------------
// PCN Exploration layer. B=4, S=1024, D=1024, NS=8, NT=10.
// hyp = a*(hidden + 0.1*expl) + (1-a)*cp + sum_j c_j*noise_j  (a=0.99^10)
// Round 8: k_fused restructured: hyp panel kept ONLY in global (L2-hot),
// A+B fragments read direct from L2 with unroll-8 reg pipelines, no in-loop
// barriers (5 per block total), LN stats fused into GEMM epilogue, LDS 33.7KB
// -> 4 blocks/CU (16 waves). Small prep kernels merged.
// ---------------------------------------------------------------------------

#define NS_ 8
#define B_ 4
#define S_ 1024
#define D_ 1024
#define NROWS (NS_*B_*S_)            // 32768
#define NELEM (1u<<25)

typedef __attribute__((ext_vector_type(8))) short short8;
typedef __attribute__((ext_vector_type(4))) float f32x4;

struct RngParams {
  uint32_t k0[10], k1[10];
  float coef[10];
  float aH, aCP;
};

// ----------------------------- threefry -----------------------------------
__host__ __device__ __forceinline__ uint32_t rotl32_(uint32_t x, int r) {
  return (x << r) | (x >> (32 - r));
}

__host__ __device__ __forceinline__ void tf2x32(uint32_t k0, uint32_t k1,
                                                uint32_t x0, uint32_t x1,
                                                uint32_t &o0, uint32_t &o1) {
  uint32_t k2 = k0 ^ k1 ^ 0x1BD11BDAu;
  x0 += k0; x1 += k1;
  x0 += x1; x1 = rotl32_(x1, 13); x1 ^= x0;
  x0 += x1; x1 = rotl32_(x1, 15); x1 ^= x0;
  x0 += x1; x1 = rotl32_(x1, 26); x1 ^= x0;
  x0 += x1; x1 = rotl32_(x1, 6);  x1 ^= x0;
  x0 += k1; x1 += k2 + 1u;
  x0 += x1; x1 = rotl32_(x1, 17); x1 ^= x0;
  x0 += x1; x1 = rotl32_(x1, 29); x1 ^= x0;
  x0 += x1; x1 = rotl32_(x1, 16); x1 ^= x0;
  x0 += x1; x1 = rotl32_(x1, 24); x1 ^= x0;
  x0 += k2; x1 += k0 + 2u;
  x0 += x1; x1 = rotl32_(x1, 13); x1 ^= x0;
  x0 += x1; x1 = rotl32_(x1, 15); x1 ^= x0;
  x0 += x1; x1 = rotl32_(x1, 26); x1 ^= x0;
  x0 += x1; x1 = rotl32_(x1, 6);  x1 ^= x0;
  x0 += k0; x1 += k1 + 3u;
  x0 += x1; x1 = rotl32_(x1, 17); x1 ^= x0;
  x0 += x1; x1 = rotl32_(x1, 29); x1 ^= x0;
  x0 += x1; x1 = rotl32_(x1, 16); x1 ^= x0;
  x0 += x1; x1 = rotl32_(x1, 24); x1 ^= x0;
  x0 += k1; x1 += k2 + 4u;
  x0 += x1; x1 = rotl32_(x1, 13); x1 ^= x0;
  x0 += x1; x1 = rotl32_(x1, 15); x1 ^= x0;
  x0 += x1; x1 = rotl32_(x1, 26); x1 ^= x0;
  x0 += x1; x1 = rotl32_(x1, 6);  x1 ^= x0;
  x0 += k2; x1 += k0 + 5u;
  o0 = x0; o1 = x1;
}

// bits -> N(0,1): XLA ErfInv32 poly; fast -log(1-x^2) via (1-x)(1+x)
__device__ __forceinline__ float bits_to_normal(uint32_t bits) {
  const float lo = -0.99999994f;
  float f = __uint_as_float((bits >> 9) | 0x3f800000u) - 1.0f;
  float x = fmaxf(lo, f * 2.0f + lo);
  float t = (1.0f - x) * (1.0f + x);
  float w = -__logf(t);
  float p;
  if (w < 5.0f) {
    w = w - 2.5f;
    p = 2.81022636e-08f;
    p = fmaf(p, w, 3.43273939e-07f);
    p = fmaf(p, w, -3.5233877e-06f);
    p = fmaf(p, w, -4.39150654e-06f);
    p = fmaf(p, w, 0.00021858087f);
    p = fmaf(p, w, -0.00125372503f);
    p = fmaf(p, w, -0.00417768164f);
    p = fmaf(p, w, 0.246640727f);
    p = fmaf(p, w, 1.50140941f);
  } else {
    w = sqrtf(w) - 3.0f;
    p = -0.000200214257f;
    p = fmaf(p, w, 0.000100950558f);
    p = fmaf(p, w, 0.00134934322f);
    p = fmaf(p, w, -0.00367342844f);
    p = fmaf(p, w, 0.00573950773f);
    p = fmaf(p, w, -0.0076224613f);
    p = fmaf(p, w, 0.00943887047f);
    p = fmaf(p, w, 1.00167406f);
    p = fmaf(p, w, 2.83297682f);
  }
  return 1.41421356f * (p * x);
}

__device__ __forceinline__ float noise10(const RngParams& P, uint32_t i) {
  float acc = 0.f;
  #pragma unroll
  for (int j = 0; j < 10; ++j) {
    uint32_t w0, w1;
    tf2x32(P.k0[j], P.k1[j], 0u, i, w0, w1);
    acc = fmaf(P.coef[j], bits_to_normal(w0 ^ w1), acc);
  }
  return acc;
}

__device__ __forceinline__ uint16_t bf16u(float x) {
  __hip_bfloat16 h = __float2bfloat16(x);
  return *(uint16_t*)&h;
}
__device__ __forceinline__ float bf2f(uint32_t u) {
  return __uint_as_float(u << 16);
}

// ----------------------------- prep (merged) -------------------------------
// blocks 0..255: Ew1 transpose->bf16 (1024x1024); 256..383: Ew2 (1024x512);
// 384..639: ctx partial sums.
__device__ void wcvt_body(const float* __restrict__ src, uint16_t* __restrict__ dst,
                          int K, int N, int bx, int by) {
  __shared__ float tile[64][65];
  int n0 = bx * 64, k0 = by * 64;
  int tid = threadIdx.x;
  #pragma unroll
  for (int i = 0; i < 16; ++i) {
    int lin = tid + i * 256;
    int tr = lin >> 6, tc = lin & 63;
    tile[tr][tc] = src[(size_t)(k0 + tr) * N + n0 + tc];
  }
  __syncthreads();
  #pragma unroll
  for (int i = 0; i < 8; ++i) {
    int lin = tid + i * 256;
    int tr = lin >> 5, tc2 = (lin & 31) * 2;
    uint32_t pk = (uint32_t)bf16u(tile[tc2][tr]) | ((uint32_t)bf16u(tile[tc2 + 1][tr]) << 16);
    *(uint32_t*)(&dst[(size_t)(n0 + tr) * K + k0 + tc2]) = pk;
  }
}

__global__ void k_prep(const float* __restrict__ Ew1, const float* __restrict__ Ew2,
                       const float* __restrict__ hidden,
                       uint16_t* __restrict__ WT1, uint16_t* __restrict__ WT2,
                       float* __restrict__ part) {
  int bi = blockIdx.x;
  if (bi < 256) {
    wcvt_body(Ew1, WT1, 1024, 1024, bi & 15, bi >> 4);
  } else if (bi < 384) {
    int j = bi - 256;
    wcvt_body(Ew2, WT2, 1024, 512, j & 7, j >> 3);
  } else {
    int cb = bi - 384;                       // 0..255
    int b = cb >> 6, ch = cb & 63;
    const float* p = hidden + (size_t)b * (S_ * D_) + (size_t)ch * 16 * 1024;
    int tid = threadIdx.x;
    #pragma unroll
    for (int k = 0; k < 4; ++k) {
      int d = tid + k * 256;
      float s = 0.f;
      #pragma unroll
      for (int t = 0; t < 16; ++t) s += p[t * 1024 + d];
      part[(size_t)cb * 1024 + d] = s;
    }
  }
}

__global__ void k_ctxB(const float* __restrict__ part, float* __restrict__ ctx) {
  int idx = blockIdx.x * 256 + threadIdx.x;
  int b = idx >> 10, d = idx & 1023;
  float s = 0.f;
  #pragma unroll 8
  for (int c = 0; c < 64; ++c) s += part[((size_t)(b * 64 + c)) * 1024 + d];
  ctx[idx] = s * (1.0f / 1024.0f);
}

__global__ void k_fc1(const float* __restrict__ ctx, const float* __restrict__ W1,
                      const float* __restrict__ b1, float* __restrict__ t1) {
  __shared__ float red[4][64];
  int b = blockIdx.x >> 5;
  int j0 = (blockIdx.x & 31) * 64;
  int l = threadIdx.x & 63, w = threadIdx.x >> 6;
  int j = j0 + l;
  const float* c = ctx + b * 1024 + w * 256;
  const float* wp = W1 + (size_t)(w * 256) * 2048 + j;
  float s = 0.f;
  #pragma unroll 8
  for (int k = 0; k < 256; ++k) s += c[k] * wp[(size_t)k * 2048];
  red[w][l] = s; __syncthreads();
  if (w == 0)
    t1[b * 2048 + j] = red[0][l] + red[1][l] + red[2][l] + red[3][l] + b1[j];
}

__global__ void k_ln_relu(float* __restrict__ t1, const float* __restrict__ g,
                          const float* __restrict__ bb) {
  __shared__ float red[256];
  int row = blockIdx.x, tid = threadIdx.x;
  float* x = t1 + row * 2048;
  float v[8];
  #pragma unroll
  for (int q = 0; q < 8; ++q) v[q] = x[tid + q * 256];
  float s = 0.f;
  #pragma unroll
  for (int q = 0; q < 8; ++q) s += v[q];
  red[tid] = s; __syncthreads();
  for (int off = 128; off > 0; off >>= 1) { if (tid < off) red[tid] += red[tid + off]; __syncthreads(); }
  float m = red[0] * (1.0f / 2048.0f);
  __syncthreads();
  float s2 = 0.f;
  #pragma unroll
  for (int q = 0; q < 8; ++q) { float d = v[q] - m; s2 += d * d; }
  red[tid] = s2; __syncthreads();
  for (int off = 128; off > 0; off >>= 1) { if (tid < off) red[tid] += red[tid + off]; __syncthreads(); }
  float var = red[0] * (1.0f / 2048.0f);
  float rs = 1.0f / sqrtf(var + 1e-5f);
  #pragma unroll
  for (int q = 0; q < 8; ++q) {
    int j = tid + q * 256;
    float z = (v[q] - m) * rs * g[j] + bb[j];
    x[j] = fmaxf(z, 0.0f);
  }
}

__global__ void k_fc2(const float* __restrict__ t1, const float* __restrict__ W2,
                      const float* __restrict__ b2, const float* __restrict__ ctx,
                      const float* __restrict__ Ew1c, const float* __restrict__ Eb1,
                      float* __restrict__ cp, float* __restrict__ ce) {
  __shared__ float red[4][64];
  int b = blockIdx.x >> 4;
  int j0 = (blockIdx.x & 15) * 64;
  int l = threadIdx.x & 63, w = threadIdx.x >> 6;
  int j = j0 + l;
  float s = 0.f;
  if (blockIdx.y == 0) {
    const float* a = t1 + b * 2048 + w * 512;
    const float* wp = W2 + (size_t)(w * 512) * 1024 + j;
    #pragma unroll 8
    for (int k = 0; k < 512; ++k) s += a[k] * wp[(size_t)k * 1024];
  } else {
    const float* a = ctx + b * 1024 + w * 256;
    const float* wp = Ew1c + (size_t)(w * 256) * 1024 + j;
    #pragma unroll 8
    for (int k = 0; k < 256; ++k) s += a[k] * wp[(size_t)k * 1024];
  }
  red[w][l] = s; __syncthreads();
  if (w == 0) {
    float r = red[0][l] + red[1][l] + red[2][l] + red[3][l];
    if (blockIdx.y == 0) cp[b * 1024 + j] = r + b2[j];
    else                 ce[b * 1024 + j] = r + Eb1[j];
  }
}

// ----------------------------- fused energy --------------------------------
// 2048 blocks x 256 thr; block = 16 rows.
// BIG: LDS = Zpan 32KB + scratch (~33.7KB) -> 4 blocks/CU. A from global L2.
// !BIG: + Apan 32KB (hyp kept in LDS; select regenerates noise).
#define ZP_OF   0
#define RED2_OF 32768
#define STM_OF  33280
#define STR_OF  33344
#define RED_OF  33408
#define APAN_OF 33664

__device__ __forceinline__ int pswz(int row, int byteInRow) {   // panel swizzle
  return (row * 2048 + byteInRow) ^ ((row & 7) << 4);
}

template<bool BIG>
__global__ __launch_bounds__(256, 4) void k_fused(
    const float* __restrict__ hidden, const float* __restrict__ cp,
    const float* __restrict__ ce, uint32_t* __restrict__ hypPairs,
    const uint16_t* __restrict__ WT1, const uint16_t* __restrict__ WT2,
    const float* __restrict__ Eln_g, const float* __restrict__ Eln_b,
    const float* __restrict__ Eb2, const float* __restrict__ Ew3,
    float* __restrict__ erows, RngParams P)
{
  __shared__ __align__(16) char smem[BIG ? 33664 : 66432];
  const int tid = threadIdx.x;
  const int lane = tid & 63;
  const int w = tid >> 6;
  const int rl = lane & 15;
  const int kg = lane >> 4;
  const int r0 = blockIdx.x * 16;
  const int bidx = (r0 >> 10) & 3;
  float* rowm = (float*)(smem + STM_OF);
  float* rowr = (float*)(smem + STR_OF);
  float* red  = (float*)(smem + RED_OF);
  float* red2 = (float*)(smem + RED2_OF);    // [4 waves][16 rows][2]

  // ---- phase 1: threefry noise + hyp (bf16 pairs) -> global (and LDS if !BIG)
  for (int q = 0; q < 32; ++q) {
    int p = tid + q * 256;                 // pair index in panel [0,8192)
    int row = p >> 9, c0 = (p & 511) * 2;
    uint32_t i0 = (uint32_t)(r0 + row) * 1024u + (uint32_t)c0;
    float nz0 = noise10(P, i0);
    float nz1 = noise10(P, i0 + 1u);
    float2 hv = *(const float2*)(hidden + (i0 & 0x3FFFFFu));
    float2 cv = *(const float2*)(cp + (bidx << 10) + c0);
    float h0 = fmaf(P.aH, hv.x, fmaf(P.aCP, cv.x, nz0));
    float h1 = fmaf(P.aH, hv.y, fmaf(P.aCP, cv.y, nz1));
    uint32_t pk = (uint32_t)bf16u(h0) | ((uint32_t)bf16u(h1) << 16);
    if (BIG) hypPairs[i0 >> 1] = pk;                       // coalesced stream
    else *(uint32_t*)(smem + APAN_OF + pswz(row, c0 * 2)) = pk;
  }
  __syncthreads();   // drains stores; hyp visible in L2 for this block

  // ---- phase 2: Y = A @ WT1 + ce -> Zpan (bf16), stats fused ----
  float s1a[4] = {0.f, 0.f, 0.f, 0.f};
  float s2a[4] = {0.f, 0.f, 0.f, 0.f};
  const uint16_t* Abase = (const uint16_t*)hypPairs + (size_t)(r0 + rl) * 1024 + kg * 8;
  for (int g = 0; g < 4; ++g) {
    f32x4 acc[4] = {};
    const uint16_t* b0 = WT1 + (size_t)(g * 256 + w * 64 +  0 + rl) * 1024 + kg * 8;
    const uint16_t* b1p = WT1 + (size_t)(g * 256 + w * 64 + 16 + rl) * 1024 + kg * 8;
    const uint16_t* b2p = WT1 + (size_t)(g * 256 + w * 64 + 32 + rl) * 1024 + kg * 8;
    const uint16_t* b3p = WT1 + (size_t)(g * 256 + w * 64 + 48 + rl) * 1024 + kg * 8;
    #pragma unroll 8
    for (int kt = 0; kt < 32; ++kt) {
      short8 af;
      if (BIG) af = *(const short8*)(Abase + kt * 32);
      else     af = *(const short8*)(smem + APAN_OF + pswz(rl, kt * 64 + kg * 16));
      short8 f0 = *(const short8*)(b0  + kt * 32);
      short8 f1 = *(const short8*)(b1p + kt * 32);
      short8 f2 = *(const short8*)(b2p + kt * 32);
      short8 f3 = *(const short8*)(b3p + kt * 32);
      acc[0] = __builtin_amdgcn_mfma_f32_16x16x32_bf16(af, f0, acc[0], 0, 0, 0);
      acc[1] = __builtin_amdgcn_mfma_f32_16x16x32_bf16(af, f1, acc[1], 0, 0, 0);
      acc[2] = __builtin_amdgcn_mfma_f32_16x16x32_bf16(af, f2, acc[2], 0, 0, 0);
      acc[3] = __builtin_amdgcn_mfma_f32_16x16x32_bf16(af, f3, acc[3], 0, 0, 0);
    }
    // epilogue: + ce, accumulate LN stats (f32), write Zpan bf16
    #pragma unroll
    for (int j = 0; j < 4; ++j) {
      int C = g * 256 + w * 64 + j * 16 + rl;
      float cev = ce[(bidx << 10) + C];
      #pragma unroll
      for (int i = 0; i < 4; ++i) {
        float y = acc[j][i] + cev;
        s1a[i] += y;
        s2a[i] = fmaf(y, y, s2a[i]);
        *(uint16_t*)(smem + ZP_OF + pswz(kg * 4 + i, C * 2)) = bf16u(y);
      }
    }
  }
  // reduce stats over the 16 lanes (rl) sharing rows kg*4+i
  #pragma unroll
  for (int i = 0; i < 4; ++i) {
    #pragma unroll
    for (int m = 1; m < 16; m <<= 1) {
      s1a[i] += __shfl_xor(s1a[i], m);
      s2a[i] += __shfl_xor(s2a[i], m);
    }
  }
  if (rl == 0) {
    #pragma unroll
    for (int i = 0; i < 4; ++i) {
      red2[(w * 16 + kg * 4 + i) * 2 + 0] = s1a[i];
      red2[(w * 16 + kg * 4 + i) * 2 + 1] = s2a[i];
    }
  }
  __syncthreads();

  // ---- finalize LN stats (16 rows) ----
  if (tid < 16) {
    float s1 = 0.f, s2 = 0.f;
    #pragma unroll
    for (int wv = 0; wv < 4; ++wv) {
      s1 += red2[(wv * 16 + tid) * 2 + 0];
      s2 += red2[(wv * 16 + tid) * 2 + 1];
    }
    float m = s1 * (1.0f / 1024.0f);
    float var = fmaxf(s2 * (1.0f / 1024.0f) - m * m, 0.0f);
    rowm[tid] = m;
    rowr[tid] = 1.0f / sqrtf(var + 1e-5f);
  }
  __syncthreads();

  // ---- phase 4: Z = relu(LN(Y)) in place ----
  for (int q = 0; q < 64; ++q) {
    int e = tid + q * 256;
    int row = e >> 10, col = e & 1023;
    uint16_t* zp = (uint16_t*)(smem + ZP_OF + pswz(row, col * 2));
    float v = bf2f(*zp);
    float z = (v - rowm[row]) * rowr[row] * Eln_g[col] + Eln_b[col];
    *zp = bf16u(fmaxf(z, 0.f));
  }
  __syncthreads();

  // ---- phase 5: U = relu(Z @ WT2 + Eb2); ep = U . Ew3 ----
  float ep0 = 0.f, ep1 = 0.f, ep2 = 0.f, ep3 = 0.f;
  for (int g = 0; g < 2; ++g) {
    f32x4 acc[4] = {};
    const uint16_t* b0 = WT2 + (size_t)(g * 256 + w * 64 +  0 + rl) * 1024 + kg * 8;
    const uint16_t* b1p = WT2 + (size_t)(g * 256 + w * 64 + 16 + rl) * 1024 + kg * 8;
    const uint16_t* b2p = WT2 + (size_t)(g * 256 + w * 64 + 32 + rl) * 1024 + kg * 8;
    const uint16_t* b3p = WT2 + (size_t)(g * 256 + w * 64 + 48 + rl) * 1024 + kg * 8;
    #pragma unroll 8
    for (int kt = 0; kt < 32; ++kt) {
      short8 af = *(const short8*)(smem + ZP_OF + pswz(rl, kt * 64 + kg * 16));
      short8 f0 = *(const short8*)(b0  + kt * 32);
      short8 f1 = *(const short8*)(b1p + kt * 32);
      short8 f2 = *(const short8*)(b2p + kt * 32);
      short8 f3 = *(const short8*)(b3p + kt * 32);
      acc[0] = __builtin_amdgcn_mfma_f32_16x16x32_bf16(af, f0, acc[0], 0, 0, 0);
      acc[1] = __builtin_amdgcn_mfma_f32_16x16x32_bf16(af, f1, acc[1], 0, 0, 0);
      acc[2] = __builtin_amdgcn_mfma_f32_16x16x32_bf16(af, f2, acc[2], 0, 0, 0);
      acc[3] = __builtin_amdgcn_mfma_f32_16x16x32_bf16(af, f3, acc[3], 0, 0, 0);
    }
    #pragma unroll
    for (int j = 0; j < 4; ++j) {
      int C = g * 256 + w * 64 + j * 16 + rl;
      float eb = Eb2[C], w3 = Ew3[C];
      ep0 = fmaf(fmaxf(acc[j][0] + eb, 0.f), w3, ep0);
      ep1 = fmaf(fmaxf(acc[j][1] + eb, 0.f), w3, ep1);
      ep2 = fmaf(fmaxf(acc[j][2] + eb, 0.f), w3, ep2);
      ep3 = fmaf(fmaxf(acc[j][3] + eb, 0.f), w3, ep3);
    }
  }
  #pragma unroll
  for (int m = 1; m < 16; m <<= 1) {
    ep0 += __shfl_xor(ep0, m);
    ep1 += __shfl_xor(ep1, m);
    ep2 += __shfl_xor(ep2, m);
    ep3 += __shfl_xor(ep3, m);
  }
  if (rl == 0) {
    red[w * 16 + kg * 4 + 0] = ep0;
    red[w * 16 + kg * 4 + 1] = ep1;
    red[w * 16 + kg * 4 + 2] = ep2;
    red[w * 16 + kg * 4 + 3] = ep3;
  }
  __syncthreads();
  if (tid < 16)
    erows[r0 + tid] = red[tid] + red[16 + tid] + red[32 + tid] + red[48 + tid];
}

// energies[nb] = mean_s erows + Eb3
__global__ void k_energy(const float* __restrict__ erows, const float* __restrict__ Eb3,
                         float* __restrict__ energ) {
  __shared__ float red[256];
  int nb = blockIdx.x, tid = threadIdx.x;
  const float* x = erows + nb * 1024;
  float s = x[tid] + x[tid + 256] + x[tid + 512] + x[tid + 768];
  red[tid] = s; __syncthreads();
  for (int off = 128; off > 0; off >>= 1) { if (tid < off) red[tid] += red[tid + off]; __syncthreads(); }
  if (tid == 0) energ[nb] = red[0] * (1.0f / 1024.0f) + Eb3[0];
}

// ----------------------------- select --------------------------------------
template<bool BIG>
__global__ __launch_bounds__(256) void k_select(
    const float* __restrict__ hidden, const float* __restrict__ cp,
    const float* __restrict__ energ, const uint32_t* __restrict__ hypPairs,
    float* __restrict__ out, RngParams P)
{
  uint32_t pe = blockIdx.x * 256u + threadIdx.x;   // pair in [0, 2^21)
  uint32_t i0 = pe * 2u;
  uint32_t b = (i0 >> 20) & 3u;
  float e[8];
  #pragma unroll
  for (int n = 0; n < 8; ++n) e[n] = -energ[n * 4 + b];
  float mx = e[0];
  #pragma unroll
  for (int n = 1; n < 8; ++n) mx = fmaxf(mx, e[n]);
  float p[8]; float s = 0.f;
  #pragma unroll
  for (int n = 0; n < 8; ++n) { p[n] = expf(e[n] - mx); s += p[n]; }
  float inv = 1.0f / s;
  float a0 = 0.f, a1 = 0.f;
  if (BIG) {
    #pragma unroll
    for (int n = 0; n < 8; ++n) {
      uint32_t pk = hypPairs[pe + ((uint32_t)n << 21)];
      a0 = fmaf(p[n], __uint_as_float(pk << 16), a0);           // low bf16
      a1 = fmaf(p[n], __uint_as_float(pk & 0xffff0000u), a1);   // high bf16
    }
    *(float2*)(out + i0) = make_float2(a0 * inv, a1 * inv);
  } else {
    float2 hv = *(const float2*)(hidden + i0);
    float2 cv = *(const float2*)(cp + ((b << 10) | (i0 & 1023u)));
    #pragma unroll
    for (int n = 0; n < 8; ++n) {
      a0 = fmaf(p[n], noise10(P, i0 + ((uint32_t)n << 22)), a0);
      a1 = fmaf(p[n], noise10(P, i0 + 1u + ((uint32_t)n << 22)), a1);
    }
    float o0 = fmaf(P.aH, hv.x, P.aCP * cv.x) + a0 * inv;
    float o1 = fmaf(P.aH, hv.y, P.aCP * cv.y) + a1 * inv;
    *(float2*)(out + i0) = make_float2(o0, o1);
  }
}

// ---------------------------------------------------------------------------
extern "C" void kernel_launch(void* const* d_in, const int* in_sizes, int n_in,
                              void* d_out, int out_size, void* d_ws, size_t ws_size,
                              hipStream_t stream) {
  const float* hidden = (const float*)d_in[0];
  const float* W1    = (const float*)d_in[1];
  const float* b1    = (const float*)d_in[2];
  const float* ln1_g = (const float*)d_in[3];
  const float* ln1_b = (const float*)d_in[4];
  const float* W2    = (const float*)d_in[5];
  const float* b2    = (const float*)d_in[6];
  const float* Ew1   = (const float*)d_in[7];
  const float* Eb1   = (const float*)d_in[8];
  const float* Eln_g = (const float*)d_in[9];
  const float* Eln_b = (const float*)d_in[10];
  const float* Ew2   = (const float*)d_in[11];
  const float* Eb2   = (const float*)d_in[12];
  const float* Ew3   = (const float*)d_in[13];
  const float* Eb3   = (const float*)d_in[14];
  float* out = (float*)d_out;

  // ws carve: hyp-bf16 64 MiB + WT1 2 MiB + WT2 1 MiB + part 1 MiB + smalls
  const size_t HYP_B  = (size_t)NELEM * 2;           // 64 MiB (bf16 pairs)
  const size_t WT1_B  = 1024ull * 1024 * 2;          // 2 MiB
  const size_t WT2_B  = 512ull * 1024 * 2;           // 1 MiB
  const size_t PART_B = 256ull * 1024 * 4;           // 1 MiB
  const size_t SMALL_B = (4096 + 8192 + 4096 + 4096 + 32768 + 32) * 4;
  bool big = ws_size >= HYP_B + WT1_B + WT2_B + PART_B + SMALL_B + 1024;

  char* ws = (char*)d_ws;
  uint32_t* hypPairs = nullptr;
  size_t off = 0;
  if (big) { hypPairs = (uint32_t*)ws; off += HYP_B; }
  uint16_t* WT1 = (uint16_t*)(ws + off); off += WT1_B;
  uint16_t* WT2 = (uint16_t*)(ws + off); off += WT2_B;
  float* part  = (float*)(ws + off);     off += PART_B;
  float* ctx   = (float*)(ws + off);
  float* t1    = ctx + 4096;
  float* cp    = t1 + 8192;
  float* ce    = cp + 4096;
  float* erows = ce + 4096;
  float* energ = erows + 32768;

  // host-side RNG params
  RngParams P;
  for (uint32_t t = 0; t < 10; ++t) {
    uint32_t o0, o1;
    tf2x32(0u, 42u, 0u, t, o0, o1);
    P.k0[t] = o0; P.k1[t] = o1;
  }
  double a = pow(0.99, 10);
  P.coef[0] = (float)(0.1 * a);
  for (int j = 1; j <= 9; ++j) P.coef[j] = (float)(0.01 * pow(0.99, 10 - j));
  P.aH = (float)a;
  P.aCP = (float)(1.0 - a);

  k_prep<<<640, 256, 0, stream>>>(Ew1, Ew2, hidden, WT1, WT2, part);
  k_ctxB<<<16, 256, 0, stream>>>(part, ctx);
  k_fc1<<<128, 256, 0, stream>>>(ctx, W1, b1, t1);
  k_ln_relu<<<4, 256, 0, stream>>>(t1, ln1_g, ln1_b);
  k_fc2<<<dim3(64, 2), 256, 0, stream>>>(t1, W2, b2, ctx, Ew1 + (size_t)1024 * 1024, Eb1, cp, ce);
  if (big)
    k_fused<true><<<2048, 256, 0, stream>>>(hidden, cp, ce, hypPairs, WT1, WT2,
                                            Eln_g, Eln_b, Eb2, Ew3, erows, P);
  else
    k_fused<false><<<2048, 256, 0, stream>>>(hidden, cp, ce, (uint32_t*)ws, WT1, WT2,
                                             Eln_g, Eln_b, Eb2, Ew3, erows, P);
  k_energy<<<32, 256, 0, stream>>>(erows, Eb3, energ);
  if (big)
    k_select<true><<<8192, 256, 0, stream>>>(hidden, cp, energ, hypPairs, out, P);
  else
    k_select<false><<<8192, 256, 0, stream>>>(hidden, cp, energ, nullptr, out, P);
}

// Round 9
// 1045.478 us; speedup vs baseline: 1.8529x; 1.0490x over previous
//
#include <hip/hip_runtime.h>
#include <hip/hip_bf16.h>
#include <stdint.h>
#include <math.h>

// ---------------------------------------------------------------------------
// PCN Exploration layer. B=4, S=1024, D=1024, NS=8, NT=10.
// hyp = a*(hidden + 0.1*expl) + (1-a)*cp + sum_j c_j*noise_j  (a=0.99^10)
// Round 9: r8 structure + hot-loop surgery: rotates via __builtin_rotateleft32
// (v_alignbit), erfinv evaluated in log2 domain (raw v_log_f32, ln2 folded
// into poly coeffs), sqrt2 folded into coeffs, fused uniform map, unroll-2
// noise pair loop. Math equivalent to <=1e-5 in erfinv units.
// ---------------------------------------------------------------------------

#define NS_ 8
#define B_ 4
#define S_ 1024
#define D_ 1024
#define NROWS (NS_*B_*S_)            // 32768
#define NELEM (1u<<25)

typedef __attribute__((ext_vector_type(8))) short short8;
typedef __attribute__((ext_vector_type(4))) float f32x4;

struct RngParams {
  uint32_t k0[10], k1[10];
  float coef[10];
  float aH, aCP;
};

// ----------------------------- threefry -----------------------------------
__host__ __device__ __forceinline__ uint32_t rotl32_(uint32_t x, int r) {
#if defined(__HIP_DEVICE_COMPILE__)
  return __builtin_rotateleft32(x, (uint32_t)r);   // v_alignbit_b32
#else
  return (x << r) | (x >> (32 - r));
#endif
}

__host__ __device__ __forceinline__ void tf2x32(uint32_t k0, uint32_t k1,
                                                uint32_t x0, uint32_t x1,
                                                uint32_t &o0, uint32_t &o1) {
  uint32_t k2 = k0 ^ k1 ^ 0x1BD11BDAu;
  x0 += k0; x1 += k1;
  x0 += x1; x1 = rotl32_(x1, 13); x1 ^= x0;
  x0 += x1; x1 = rotl32_(x1, 15); x1 ^= x0;
  x0 += x1; x1 = rotl32_(x1, 26); x1 ^= x0;
  x0 += x1; x1 = rotl32_(x1, 6);  x1 ^= x0;
  x0 += k1; x1 += k2 + 1u;
  x0 += x1; x1 = rotl32_(x1, 17); x1 ^= x0;
  x0 += x1; x1 = rotl32_(x1, 29); x1 ^= x0;
  x0 += x1; x1 = rotl32_(x1, 16); x1 ^= x0;
  x0 += x1; x1 = rotl32_(x1, 24); x1 ^= x0;
  x0 += k2; x1 += k0 + 2u;
  x0 += x1; x1 = rotl32_(x1, 13); x1 ^= x0;
  x0 += x1; x1 = rotl32_(x1, 15); x1 ^= x0;
  x0 += x1; x1 = rotl32_(x1, 26); x1 ^= x0;
  x0 += x1; x1 = rotl32_(x1, 6);  x1 ^= x0;
  x0 += k0; x1 += k1 + 3u;
  x0 += x1; x1 = rotl32_(x1, 17); x1 ^= x0;
  x0 += x1; x1 = rotl32_(x1, 29); x1 ^= x0;
  x0 += x1; x1 = rotl32_(x1, 16); x1 ^= x0;
  x0 += x1; x1 = rotl32_(x1, 24); x1 ^= x0;
  x0 += k1; x1 += k2 + 4u;
  x0 += x1; x1 = rotl32_(x1, 13); x1 ^= x0;
  x0 += x1; x1 = rotl32_(x1, 15); x1 ^= x0;
  x0 += x1; x1 = rotl32_(x1, 26); x1 ^= x0;
  x0 += x1; x1 = rotl32_(x1, 6);  x1 ^= x0;
  x0 += k2; x1 += k0 + 5u;
  o0 = x0; o1 = x1;
}

// bits -> sqrt2*erfinv(u) (the N(0,1) value), log2-domain poly.
// Main branch: v = -log2(1-x^2) - 2.5/ln2; coeffs = XLA a_k * ln2^k * sqrt2.
// Tail (w>=5 i.e. -log2t >= 5/ln2): original form, sqrt2 folded.
__device__ __forceinline__ float b2n_scaled(uint32_t bits) {
  const float lo = -0.99999994f;
  float f = __uint_as_float((bits >> 9) | 0x3f800000u);     // [1,2)
  float x = fmaxf(lo, fmaf(f, 2.0f, lo - 2.0f));            // 2f-2+lo, clamped
  float t = fmaf(-x, x, 1.0f);                              // 1 - x^2
  float l2 = __log2f(t);                                    // <= 0
  float p;
  if (l2 > -7.2134752f) {                                   // w < 5
    float v = fmaf(l2, -1.0f, -3.6067376f);                 // -l2 - 2.5/ln2
    p = 2.11766e-09f;
    p = fmaf(p, v, 3.73196e-08f);
    p = fmaf(p, v, -5.52622e-07f);
    p = fmaf(p, v, -9.93683e-07f);
    p = fmaf(p, v, 7.13556e-05f);
    p = fmaf(p, v, -5.90466e-04f);
    p = fmaf(p, v, -2.83857e-03f);
    p = fmaf(p, v, 2.41772e-01f);
    p = fmaf(p, v, 2.1233136f);
  } else {
    float s = sqrtf(l2 * -0.69314718f) - 3.0f;              // sqrt(w) - 3
    p = -2.83146e-04f;
    p = fmaf(p, s, 1.42766e-04f);
    p = fmaf(p, s, 1.90826e-03f);
    p = fmaf(p, s, -5.19503e-03f);
    p = fmaf(p, s, 8.11695e-03f);
    p = fmaf(p, s, -1.07799e-02f);
    p = fmaf(p, s, 1.33486e-02f);
    p = fmaf(p, s, 1.41658104f);
    p = fmaf(p, s, 4.00643763f);
  }
  return p * x;
}

__device__ __forceinline__ float noise10(const RngParams& P, uint32_t i) {
  float acc = 0.f;
  #pragma unroll
  for (int j = 0; j < 10; ++j) {
    uint32_t w0, w1;
    tf2x32(P.k0[j], P.k1[j], 0u, i, w0, w1);
    acc = fmaf(P.coef[j], b2n_scaled(w0 ^ w1), acc);
  }
  return acc;
}

__device__ __forceinline__ uint16_t bf16u(float x) {
  __hip_bfloat16 h = __float2bfloat16(x);
  return *(uint16_t*)&h;
}
__device__ __forceinline__ float bf2f(uint32_t u) {
  return __uint_as_float(u << 16);
}

// ----------------------------- prep (merged) -------------------------------
__device__ void wcvt_body(const float* __restrict__ src, uint16_t* __restrict__ dst,
                          int K, int N, int bx, int by) {
  __shared__ float tile[64][65];
  int n0 = bx * 64, k0 = by * 64;
  int tid = threadIdx.x;
  #pragma unroll
  for (int i = 0; i < 16; ++i) {
    int lin = tid + i * 256;
    int tr = lin >> 6, tc = lin & 63;
    tile[tr][tc] = src[(size_t)(k0 + tr) * N + n0 + tc];
  }
  __syncthreads();
  #pragma unroll
  for (int i = 0; i < 8; ++i) {
    int lin = tid + i * 256;
    int tr = lin >> 5, tc2 = (lin & 31) * 2;
    uint32_t pk = (uint32_t)bf16u(tile[tc2][tr]) | ((uint32_t)bf16u(tile[tc2 + 1][tr]) << 16);
    *(uint32_t*)(&dst[(size_t)(n0 + tr) * K + k0 + tc2]) = pk;
  }
}

__global__ void k_prep(const float* __restrict__ Ew1, const float* __restrict__ Ew2,
                       const float* __restrict__ hidden,
                       uint16_t* __restrict__ WT1, uint16_t* __restrict__ WT2,
                       float* __restrict__ part) {
  int bi = blockIdx.x;
  if (bi < 256) {
    wcvt_body(Ew1, WT1, 1024, 1024, bi & 15, bi >> 4);
  } else if (bi < 384) {
    int j = bi - 256;
    wcvt_body(Ew2, WT2, 1024, 512, j & 7, j >> 3);
  } else {
    int cb = bi - 384;
    int b = cb >> 6, ch = cb & 63;
    const float* p = hidden + (size_t)b * (S_ * D_) + (size_t)ch * 16 * 1024;
    int tid = threadIdx.x;
    #pragma unroll
    for (int k = 0; k < 4; ++k) {
      int d = tid + k * 256;
      float s = 0.f;
      #pragma unroll
      for (int t = 0; t < 16; ++t) s += p[t * 1024 + d];
      part[(size_t)cb * 1024 + d] = s;
    }
  }
}

__global__ void k_ctxB(const float* __restrict__ part, float* __restrict__ ctx) {
  int idx = blockIdx.x * 256 + threadIdx.x;
  int b = idx >> 10, d = idx & 1023;
  float s = 0.f;
  #pragma unroll 8
  for (int c = 0; c < 64; ++c) s += part[((size_t)(b * 64 + c)) * 1024 + d];
  ctx[idx] = s * (1.0f / 1024.0f);
}

__global__ void k_fc1(const float* __restrict__ ctx, const float* __restrict__ W1,
                      const float* __restrict__ b1, float* __restrict__ t1) {
  __shared__ float red[4][64];
  int b = blockIdx.x >> 5;
  int j0 = (blockIdx.x & 31) * 64;
  int l = threadIdx.x & 63, w = threadIdx.x >> 6;
  int j = j0 + l;
  const float* c = ctx + b * 1024 + w * 256;
  const float* wp = W1 + (size_t)(w * 256) * 2048 + j;
  float s = 0.f;
  #pragma unroll 8
  for (int k = 0; k < 256; ++k) s += c[k] * wp[(size_t)k * 2048];
  red[w][l] = s; __syncthreads();
  if (w == 0)
    t1[b * 2048 + j] = red[0][l] + red[1][l] + red[2][l] + red[3][l] + b1[j];
}

__global__ void k_ln_relu(float* __restrict__ t1, const float* __restrict__ g,
                          const float* __restrict__ bb) {
  __shared__ float red[256];
  int row = blockIdx.x, tid = threadIdx.x;
  float* x = t1 + row * 2048;
  float v[8];
  #pragma unroll
  for (int q = 0; q < 8; ++q) v[q] = x[tid + q * 256];
  float s = 0.f;
  #pragma unroll
  for (int q = 0; q < 8; ++q) s += v[q];
  red[tid] = s; __syncthreads();
  for (int off = 128; off > 0; off >>= 1) { if (tid < off) red[tid] += red[tid + off]; __syncthreads(); }
  float m = red[0] * (1.0f / 2048.0f);
  __syncthreads();
  float s2 = 0.f;
  #pragma unroll
  for (int q = 0; q < 8; ++q) { float d = v[q] - m; s2 += d * d; }
  red[tid] = s2; __syncthreads();
  for (int off = 128; off > 0; off >>= 1) { if (tid < off) red[tid] += red[tid + off]; __syncthreads(); }
  float var = red[0] * (1.0f / 2048.0f);
  float rs = 1.0f / sqrtf(var + 1e-5f);
  #pragma unroll
  for (int q = 0; q < 8; ++q) {
    int j = tid + q * 256;
    float z = (v[q] - m) * rs * g[j] + bb[j];
    x[j] = fmaxf(z, 0.0f);
  }
}

__global__ void k_fc2(const float* __restrict__ t1, const float* __restrict__ W2,
                      const float* __restrict__ b2, const float* __restrict__ ctx,
                      const float* __restrict__ Ew1c, const float* __restrict__ Eb1,
                      float* __restrict__ cp, float* __restrict__ ce) {
  __shared__ float red[4][64];
  int b = blockIdx.x >> 4;
  int j0 = (blockIdx.x & 15) * 64;
  int l = threadIdx.x & 63, w = threadIdx.x >> 6;
  int j = j0 + l;
  float s = 0.f;
  if (blockIdx.y == 0) {
    const float* a = t1 + b * 2048 + w * 512;
    const float* wp = W2 + (size_t)(w * 512) * 1024 + j;
    #pragma unroll 8
    for (int k = 0; k < 512; ++k) s += a[k] * wp[(size_t)k * 1024];
  } else {
    const float* a = ctx + b * 1024 + w * 256;
    const float* wp = Ew1c + (size_t)(w * 256) * 1024 + j;
    #pragma unroll 8
    for (int k = 0; k < 256; ++k) s += a[k] * wp[(size_t)k * 1024];
  }
  red[w][l] = s; __syncthreads();
  if (w == 0) {
    float r = red[0][l] + red[1][l] + red[2][l] + red[3][l];
    if (blockIdx.y == 0) cp[b * 1024 + j] = r + b2[j];
    else                 ce[b * 1024 + j] = r + Eb1[j];
  }
}

// ----------------------------- fused energy --------------------------------
#define ZP_OF   0
#define RED2_OF 32768
#define STM_OF  33280
#define STR_OF  33344
#define RED_OF  33408
#define APAN_OF 33664

__device__ __forceinline__ int pswz(int row, int byteInRow) {   // panel swizzle
  return (row * 2048 + byteInRow) ^ ((row & 7) << 4);
}

template<bool BIG>
__global__ __launch_bounds__(256, 4) void k_fused(
    const float* __restrict__ hidden, const float* __restrict__ cp,
    const float* __restrict__ ce, uint32_t* __restrict__ hypPairs,
    const uint16_t* __restrict__ WT1, const uint16_t* __restrict__ WT2,
    const float* __restrict__ Eln_g, const float* __restrict__ Eln_b,
    const float* __restrict__ Eb2, const float* __restrict__ Ew3,
    float* __restrict__ erows, RngParams P)
{
  __shared__ __align__(16) char smem[BIG ? 33664 : 66432];
  const int tid = threadIdx.x;
  const int lane = tid & 63;
  const int w = tid >> 6;
  const int rl = lane & 15;
  const int kg = lane >> 4;
  const int r0 = blockIdx.x * 16;
  const int bidx = (r0 >> 10) & 3;
  float* rowm = (float*)(smem + STM_OF);
  float* rowr = (float*)(smem + STR_OF);
  float* red  = (float*)(smem + RED_OF);
  float* red2 = (float*)(smem + RED2_OF);

  // ---- phase 1: threefry noise + hyp (bf16 pairs) -> global (LDS if !BIG) --
  #pragma unroll 2
  for (int q = 0; q < 32; ++q) {
    int p = tid + q * 256;
    int row = p >> 9, c0 = (p & 511) * 2;
    uint32_t i0 = (uint32_t)(r0 + row) * 1024u + (uint32_t)c0;
    float nz0 = noise10(P, i0);
    float nz1 = noise10(P, i0 + 1u);
    float2 hv = *(const float2*)(hidden + (i0 & 0x3FFFFFu));
    float2 cv = *(const float2*)(cp + (bidx << 10) + c0);
    float h0 = fmaf(P.aH, hv.x, fmaf(P.aCP, cv.x, nz0));
    float h1 = fmaf(P.aH, hv.y, fmaf(P.aCP, cv.y, nz1));
    uint32_t pk = (uint32_t)bf16u(h0) | ((uint32_t)bf16u(h1) << 16);
    if (BIG) hypPairs[i0 >> 1] = pk;
    else *(uint32_t*)(smem + APAN_OF + pswz(row, c0 * 2)) = pk;
  }
  __syncthreads();

  // ---- phase 2: Y = A @ WT1 + ce -> Zpan (bf16), LN stats fused ----
  float s1a[4] = {0.f, 0.f, 0.f, 0.f};
  float s2a[4] = {0.f, 0.f, 0.f, 0.f};
  const uint16_t* Abase = (const uint16_t*)hypPairs + (size_t)(r0 + rl) * 1024 + kg * 8;
  for (int g = 0; g < 4; ++g) {
    f32x4 acc[4] = {};
    const uint16_t* b0 = WT1 + (size_t)(g * 256 + w * 64 +  0 + rl) * 1024 + kg * 8;
    const uint16_t* b1p = WT1 + (size_t)(g * 256 + w * 64 + 16 + rl) * 1024 + kg * 8;
    const uint16_t* b2p = WT1 + (size_t)(g * 256 + w * 64 + 32 + rl) * 1024 + kg * 8;
    const uint16_t* b3p = WT1 + (size_t)(g * 256 + w * 64 + 48 + rl) * 1024 + kg * 8;
    #pragma unroll 8
    for (int kt = 0; kt < 32; ++kt) {
      short8 af;
      if (BIG) af = *(const short8*)(Abase + kt * 32);
      else     af = *(const short8*)(smem + APAN_OF + pswz(rl, kt * 64 + kg * 16));
      short8 f0 = *(const short8*)(b0  + kt * 32);
      short8 f1 = *(const short8*)(b1p + kt * 32);
      short8 f2 = *(const short8*)(b2p + kt * 32);
      short8 f3 = *(const short8*)(b3p + kt * 32);
      acc[0] = __builtin_amdgcn_mfma_f32_16x16x32_bf16(af, f0, acc[0], 0, 0, 0);
      acc[1] = __builtin_amdgcn_mfma_f32_16x16x32_bf16(af, f1, acc[1], 0, 0, 0);
      acc[2] = __builtin_amdgcn_mfma_f32_16x16x32_bf16(af, f2, acc[2], 0, 0, 0);
      acc[3] = __builtin_amdgcn_mfma_f32_16x16x32_bf16(af, f3, acc[3], 0, 0, 0);
    }
    #pragma unroll
    for (int j = 0; j < 4; ++j) {
      int C = g * 256 + w * 64 + j * 16 + rl;
      float cev = ce[(bidx << 10) + C];
      #pragma unroll
      for (int i = 0; i < 4; ++i) {
        float y = acc[j][i] + cev;
        s1a[i] += y;
        s2a[i] = fmaf(y, y, s2a[i]);
        *(uint16_t*)(smem + ZP_OF + pswz(kg * 4 + i, C * 2)) = bf16u(y);
      }
    }
  }
  #pragma unroll
  for (int i = 0; i < 4; ++i) {
    #pragma unroll
    for (int m = 1; m < 16; m <<= 1) {
      s1a[i] += __shfl_xor(s1a[i], m);
      s2a[i] += __shfl_xor(s2a[i], m);
    }
  }
  if (rl == 0) {
    #pragma unroll
    for (int i = 0; i < 4; ++i) {
      red2[(w * 16 + kg * 4 + i) * 2 + 0] = s1a[i];
      red2[(w * 16 + kg * 4 + i) * 2 + 1] = s2a[i];
    }
  }
  __syncthreads();

  if (tid < 16) {
    float s1 = 0.f, s2 = 0.f;
    #pragma unroll
    for (int wv = 0; wv < 4; ++wv) {
      s1 += red2[(wv * 16 + tid) * 2 + 0];
      s2 += red2[(wv * 16 + tid) * 2 + 1];
    }
    float m = s1 * (1.0f / 1024.0f);
    float var = fmaxf(s2 * (1.0f / 1024.0f) - m * m, 0.0f);
    rowm[tid] = m;
    rowr[tid] = 1.0f / sqrtf(var + 1e-5f);
  }
  __syncthreads();

  // ---- phase 4: Z = relu(LN(Y)) in place ----
  for (int q = 0; q < 64; ++q) {
    int e = tid + q * 256;
    int row = e >> 10, col = e & 1023;
    uint16_t* zp = (uint16_t*)(smem + ZP_OF + pswz(row, col * 2));
    float v = bf2f(*zp);
    float z = (v - rowm[row]) * rowr[row] * Eln_g[col] + Eln_b[col];
    *zp = bf16u(fmaxf(z, 0.f));
  }
  __syncthreads();

  // ---- phase 5: U = relu(Z @ WT2 + Eb2); ep = U . Ew3 ----
  float ep0 = 0.f, ep1 = 0.f, ep2 = 0.f, ep3 = 0.f;
  for (int g = 0; g < 2; ++g) {
    f32x4 acc[4] = {};
    const uint16_t* b0 = WT2 + (size_t)(g * 256 + w * 64 +  0 + rl) * 1024 + kg * 8;
    const uint16_t* b1p = WT2 + (size_t)(g * 256 + w * 64 + 16 + rl) * 1024 + kg * 8;
    const uint16_t* b2p = WT2 + (size_t)(g * 256 + w * 64 + 32 + rl) * 1024 + kg * 8;
    const uint16_t* b3p = WT2 + (size_t)(g * 256 + w * 64 + 48 + rl) * 1024 + kg * 8;
    #pragma unroll 8
    for (int kt = 0; kt < 32; ++kt) {
      short8 af = *(const short8*)(smem + ZP_OF + pswz(rl, kt * 64 + kg * 16));
      short8 f0 = *(const short8*)(b0  + kt * 32);
      short8 f1 = *(const short8*)(b1p + kt * 32);
      short8 f2 = *(const short8*)(b2p + kt * 32);
      short8 f3 = *(const short8*)(b3p + kt * 32);
      acc[0] = __builtin_amdgcn_mfma_f32_16x16x32_bf16(af, f0, acc[0], 0, 0, 0);
      acc[1] = __builtin_amdgcn_mfma_f32_16x16x32_bf16(af, f1, acc[1], 0, 0, 0);
      acc[2] = __builtin_amdgcn_mfma_f32_16x16x32_bf16(af, f2, acc[2], 0, 0, 0);
      acc[3] = __builtin_amdgcn_mfma_f32_16x16x32_bf16(af, f3, acc[3], 0, 0, 0);
    }
    #pragma unroll
    for (int j = 0; j < 4; ++j) {
      int C = g * 256 + w * 64 + j * 16 + rl;
      float eb = Eb2[C], w3 = Ew3[C];
      ep0 = fmaf(fmaxf(acc[j][0] + eb, 0.f), w3, ep0);
      ep1 = fmaf(fmaxf(acc[j][1] + eb, 0.f), w3, ep1);
      ep2 = fmaf(fmaxf(acc[j][2] + eb, 0.f), w3, ep2);
      ep3 = fmaf(fmaxf(acc[j][3] + eb, 0.f), w3, ep3);
    }
  }
  #pragma unroll
  for (int m = 1; m < 16; m <<= 1) {
    ep0 += __shfl_xor(ep0, m);
    ep1 += __shfl_xor(ep1, m);
    ep2 += __shfl_xor(ep2, m);
    ep3 += __shfl_xor(ep3, m);
  }
  if (rl == 0) {
    red[w * 16 + kg * 4 + 0] = ep0;
    red[w * 16 + kg * 4 + 1] = ep1;
    red[w * 16 + kg * 4 + 2] = ep2;
    red[w * 16 + kg * 4 + 3] = ep3;
  }
  __syncthreads();
  if (tid < 16)
    erows[r0 + tid] = red[tid] + red[16 + tid] + red[32 + tid] + red[48 + tid];
}

// energies[nb] = mean_s erows + Eb3
__global__ void k_energy(const float* __restrict__ erows, const float* __restrict__ Eb3,
                         float* __restrict__ energ) {
  __shared__ float red[256];
  int nb = blockIdx.x, tid = threadIdx.x;
  const float* x = erows + nb * 1024;
  float s = x[tid] + x[tid + 256] + x[tid + 512] + x[tid + 768];
  red[tid] = s; __syncthreads();
  for (int off = 128; off > 0; off >>= 1) { if (tid < off) red[tid] += red[tid + off]; __syncthreads(); }
  if (tid == 0) energ[nb] = red[0] * (1.0f / 1024.0f) + Eb3[0];
}

// ----------------------------- select --------------------------------------
template<bool BIG>
__global__ __launch_bounds__(256) void k_select(
    const float* __restrict__ hidden, const float* __restrict__ cp,
    const float* __restrict__ energ, const uint32_t* __restrict__ hypPairs,
    float* __restrict__ out, RngParams P)
{
  uint32_t pe = blockIdx.x * 256u + threadIdx.x;
  uint32_t i0 = pe * 2u;
  uint32_t b = (i0 >> 20) & 3u;
  float e[8];
  #pragma unroll
  for (int n = 0; n < 8; ++n) e[n] = -energ[n * 4 + b];
  float mx = e[0];
  #pragma unroll
  for (int n = 1; n < 8; ++n) mx = fmaxf(mx, e[n]);
  float p[8]; float s = 0.f;
  #pragma unroll
  for (int n = 0; n < 8; ++n) { p[n] = expf(e[n] - mx); s += p[n]; }
  float inv = 1.0f / s;
  float a0 = 0.f, a1 = 0.f;
  if (BIG) {
    #pragma unroll
    for (int n = 0; n < 8; ++n) {
      uint32_t pk = hypPairs[pe + ((uint32_t)n << 21)];
      a0 = fmaf(p[n], __uint_as_float(pk << 16), a0);
      a1 = fmaf(p[n], __uint_as_float(pk & 0xffff0000u), a1);
    }
    *(float2*)(out + i0) = make_float2(a0 * inv, a1 * inv);
  } else {
    float2 hv = *(const float2*)(hidden + i0);
    float2 cv = *(const float2*)(cp + ((b << 10) | (i0 & 1023u)));
    #pragma unroll
    for (int n = 0; n < 8; ++n) {
      a0 = fmaf(p[n], noise10(P, i0 + ((uint32_t)n << 22)), a0);
      a1 = fmaf(p[n], noise10(P, i0 + 1u + ((uint32_t)n << 22)), a1);
    }
    float o0 = fmaf(P.aH, hv.x, P.aCP * cv.x) + a0 * inv;
    float o1 = fmaf(P.aH, hv.y, P.aCP * cv.y) + a1 * inv;
    *(float2*)(out + i0) = make_float2(o0, o1);
  }
}

// ---------------------------------------------------------------------------
extern "C" void kernel_launch(void* const* d_in, const int* in_sizes, int n_in,
                              void* d_out, int out_size, void* d_ws, size_t ws_size,
                              hipStream_t stream) {
  const float* hidden = (const float*)d_in[0];
  const float* W1    = (const float*)d_in[1];
  const float* b1    = (const float*)d_in[2];
  const float* ln1_g = (const float*)d_in[3];
  const float* ln1_b = (const float*)d_in[4];
  const float* W2    = (const float*)d_in[5];
  const float* b2    = (const float*)d_in[6];
  const float* Ew1   = (const float*)d_in[7];
  const float* Eb1   = (const float*)d_in[8];
  const float* Eln_g = (const float*)d_in[9];
  const float* Eln_b = (const float*)d_in[10];
  const float* Ew2   = (const float*)d_in[11];
  const float* Eb2   = (const float*)d_in[12];
  const float* Ew3   = (const float*)d_in[13];
  const float* Eb3   = (const float*)d_in[14];
  float* out = (float*)d_out;

  const size_t HYP_B  = (size_t)NELEM * 2;
  const size_t WT1_B  = 1024ull * 1024 * 2;
  const size_t WT2_B  = 512ull * 1024 * 2;
  const size_t PART_B = 256ull * 1024 * 4;
  const size_t SMALL_B = (4096 + 8192 + 4096 + 4096 + 32768 + 32) * 4;
  bool big = ws_size >= HYP_B + WT1_B + WT2_B + PART_B + SMALL_B + 1024;

  char* ws = (char*)d_ws;
  uint32_t* hypPairs = nullptr;
  size_t off = 0;
  if (big) { hypPairs = (uint32_t*)ws; off += HYP_B; }
  uint16_t* WT1 = (uint16_t*)(ws + off); off += WT1_B;
  uint16_t* WT2 = (uint16_t*)(ws + off); off += WT2_B;
  float* part  = (float*)(ws + off);     off += PART_B;
  float* ctx   = (float*)(ws + off);
  float* t1    = ctx + 4096;
  float* cp    = t1 + 8192;
  float* ce    = cp + 4096;
  float* erows = ce + 4096;
  float* energ = erows + 32768;

  RngParams P;
  for (uint32_t t = 0; t < 10; ++t) {
    uint32_t o0, o1;
    tf2x32(0u, 42u, 0u, t, o0, o1);
    P.k0[t] = o0; P.k1[t] = o1;
  }
  double a = pow(0.99, 10);
  P.coef[0] = (float)(0.1 * a);
  for (int j = 1; j <= 9; ++j) P.coef[j] = (float)(0.01 * pow(0.99, 10 - j));
  P.aH = (float)a;
  P.aCP = (float)(1.0 - a);

  k_prep<<<640, 256, 0, stream>>>(Ew1, Ew2, hidden, WT1, WT2, part);
  k_ctxB<<<16, 256, 0, stream>>>(part, ctx);
  k_fc1<<<128, 256, 0, stream>>>(ctx, W1, b1, t1);
  k_ln_relu<<<4, 256, 0, stream>>>(t1, ln1_g, ln1_b);
  k_fc2<<<dim3(64, 2), 256, 0, stream>>>(t1, W2, b2, ctx, Ew1 + (size_t)1024 * 1024, Eb1, cp, ce);
  if (big)
    k_fused<true><<<2048, 256, 0, stream>>>(hidden, cp, ce, hypPairs, WT1, WT2,
                                            Eln_g, Eln_b, Eb2, Ew3, erows, P);
  else
    k_fused<false><<<2048, 256, 0, stream>>>(hidden, cp, ce, (uint32_t*)ws, WT1, WT2,
                                             Eln_g, Eln_b, Eb2, Ew3, erows, P);
  k_energy<<<32, 256, 0, stream>>>(erows, Eb3, energ);
  if (big)
    k_select<true><<<8192, 256, 0, stream>>>(hidden, cp, energ, hypPairs, out, P);
  else
    k_select<false><<<8192, 256, 0, stream>>>(hidden, cp, energ, nullptr, out, P);
}